// Round 5
// baseline (1372.515 us; speedup 1.0000x reference)
//
#include <hip/hip_runtime.h>
#include <stdint.h>

typedef __bf16 bf16;
typedef bf16 bf16x8 __attribute__((ext_vector_type(8)));
typedef bf16 bf16x4 __attribute__((ext_vector_type(4)));
typedef float f32x4 __attribute__((ext_vector_type(4)));

#define DEV __device__ __forceinline__

// ---------------------------------------------------------------- utilities

DEV void gload_lds16(const bf16* g, bf16* l) {
  __builtin_amdgcn_global_load_lds((const __attribute__((address_space(1))) void*)g,
                                   (__attribute__((address_space(3))) void*)l,
                                   16, 0, 0);
}

DEV uint32_t pkbf(float a, float b) {
  unsigned short ua = __builtin_bit_cast(unsigned short, (bf16)a);
  unsigned short ub = __builtin_bit_cast(unsigned short, (bf16)b);
  return (uint32_t)ua | ((uint32_t)ub << 16);
}

union U8 { uint32_t u[4]; bf16x8 v; };

// ---------------------------------------------------------------- f32 -> bf16

__global__ void f2b_kernel(const float* __restrict__ in, bf16* __restrict__ out, int n4) {
  int i = blockIdx.x * 256 + threadIdx.x;
  if (i < n4) {
    float4 v = ((const float4*)in)[i];
    bf16x4 o;
    o[0] = (bf16)v.x; o[1] = (bf16)v.y; o[2] = (bf16)v.z; o[3] = (bf16)v.w;
    *(bf16x4*)(out + (size_t)i * 4) = o;
  }
}

// ---------------------------------------------------------------- silu(t_emb)

__global__ void silu_kernel(const float* __restrict__ in, float* __restrict__ out, int n) {
  int i = blockIdx.x * 256 + threadIdx.x;
  if (i < n) { float v = in[i]; out[i] = v / (1.0f + __expf(-v)); }
}

// ---------------------------------------------------------------- mod = silu(t) @ ada_w^T + ada_b   [8,6912]

__global__ __launch_bounds__(256) void mod_kernel(
    const float* __restrict__ st, const float* __restrict__ ada_w,
    const float* __restrict__ ada_b, float* __restrict__ modout) {
  int gw = (blockIdx.x * 256 + threadIdx.x) >> 6;
  int lane = threadIdx.x & 63;
  if (gw >= 8 * 6912) return;
  int b = gw / 6912, j = gw % 6912;
  const float* sp = st + b * 1152;
  const float* wp = ada_w + (size_t)j * 1152;
  float acc = 0.f;
  for (int k = lane; k < 1152; k += 64) acc += sp[k] * wp[k];
  #pragma unroll
  for (int off = 32; off; off >>= 1) acc += __shfl_xor(acc, off);
  if (lane == 0) modout[(size_t)b * 6912 + j] = acc + ada_b[j];
}

// ---------------------------------------------------------------- LN + modulate -> bf16

__global__ __launch_bounds__(256) void ln_mod_kernel(
    const float* __restrict__ x, const float* __restrict__ mod,
    int sh_off, int sc_off, bf16* __restrict__ out) {
  int row = blockIdx.x, tid = threadIdx.x;
  int b = row >> 10;
  const float* xr = x + (size_t)row * 1152;
  float vals[5];
  float s = 0.f, s2 = 0.f;
  #pragma unroll
  for (int it = 0; it < 5; ++it) {
    int i = tid + it * 256;
    float v = (i < 1152) ? xr[i] : 0.f;
    vals[it] = v; s += v; s2 += v * v;
  }
  #pragma unroll
  for (int off = 32; off; off >>= 1) { s += __shfl_xor(s, off); s2 += __shfl_xor(s2, off); }
  __shared__ float rs[4], rs2[4];
  int w = tid >> 6, lane = tid & 63;
  if (lane == 0) { rs[w] = s; rs2[w] = s2; }
  __syncthreads();
  s = rs[0] + rs[1] + rs[2] + rs[3];
  s2 = rs2[0] + rs2[1] + rs2[2] + rs2[3];
  float mu = s * (1.0f / 1152.0f);
  float var = s2 * (1.0f / 1152.0f) - mu * mu;
  float rstd = rsqrtf(var + 1e-6f);
  const float* shp = mod + (size_t)b * 6912 + sh_off;
  const float* scp = mod + (size_t)b * 6912 + sc_off;
  #pragma unroll
  for (int it = 0; it < 5; ++it) {
    int i = tid + it * 256;
    if (i < 1152) {
      float v = (vals[it] - mu) * rstd;
      out[(size_t)row * 1152 + i] = (bf16)(v * (1.0f + scp[i]) + shp[i]);
    }
  }
}

// ---------------------------------------------------------------- GEMM  C = A @ W^T (+epilogues)
// A [M,K] bf16 row-major, W [N,K] bf16 row-major. 128x128 tile, BK=32, 4 waves.

DEV void stage_tile(const bf16* src, int ld, int row0, int maxrow, int k0,
                    bf16* lds, int tid) {
  int lane = tid & 63, wv = tid >> 6;
  #pragma unroll
  for (int j = 0; j < 2; ++j) {
    int r = j * 64 + wv * 16 + (lane >> 2);
    int kk = (lane & 3) * 8;
    int gr = min(row0 + r, maxrow);
    const bf16* g = src + (size_t)gr * ld + k0 + kk;
    bf16* l = lds + (j * 64 + wv * 16) * 32;   // wave-uniform base; HW adds lane*16B
    gload_lds16(g, l);
  }
}

// EP: 0 = bias -> bf16 Cb ; 1 = Cf = resid + gate*(acc+bias) (+opt bf16 Cb2) ; 2 = gelu -> bf16 Cb
template <int EP>
__global__ __launch_bounds__(256) void gemm_bt(
    const bf16* __restrict__ A, int lda,
    const bf16* __restrict__ W, int ldw,
    const float* __restrict__ bias,
    bf16* __restrict__ Cb, int ldc,
    float* __restrict__ Cf,
    const float* __restrict__ resid,
    const float* __restrict__ gate, int gate_off,
    bf16* __restrict__ Cb2,
    int M, int N, int K) {
  __shared__ __align__(16) bf16 lA[128 * 32];
  __shared__ __align__(16) bf16 lB[128 * 32];
  int tid = threadIdx.x, lane = tid & 63, w = tid >> 6;
  int wr = w >> 1, wc = w & 1;
  int row0 = blockIdx.x * 128, col0 = blockIdx.y * 128;
  f32x4 acc[4][4] = {};
  int nk = K >> 5;
  int rbase = wr * 64 + (lane & 15);
  int cbase = wc * 64 + (lane & 15);
  int koff = (lane >> 4) * 8;
  for (int ks = 0; ks < nk; ++ks) {
    stage_tile(A, lda, row0, M - 1, ks * 32, lA, tid);
    stage_tile(W, ldw, col0, N - 1, ks * 32, lB, tid);
    __syncthreads();           // drains vmcnt(0) for global_load_lds, then barrier
    bf16x8 af[4], bg[4];
    #pragma unroll
    for (int i = 0; i < 4; ++i) af[i] = *(const bf16x8*)&lA[(rbase + i * 16) * 32 + koff];
    #pragma unroll
    for (int i = 0; i < 4; ++i) bg[i] = *(const bf16x8*)&lB[(cbase + i * 16) * 32 + koff];
    #pragma unroll
    for (int mi = 0; mi < 4; ++mi)
      #pragma unroll
      for (int ni = 0; ni < 4; ++ni)
        acc[mi][ni] = __builtin_amdgcn_mfma_f32_16x16x32_bf16(af[mi], bg[ni], acc[mi][ni], 0, 0, 0);
    __syncthreads();
  }
  int r0 = row0 + wr * 64, c0 = col0 + wc * 64;
  #pragma unroll
  for (int mi = 0; mi < 4; ++mi)
    #pragma unroll
    for (int ni = 0; ni < 4; ++ni)
      #pragma unroll
      for (int rg = 0; rg < 4; ++rg) {
        int r = r0 + mi * 16 + (lane >> 4) * 4 + rg;
        int cc = c0 + ni * 16 + (lane & 15);
        if (r < M) {
          float v = acc[mi][ni][rg];
          if (bias) v += bias[cc];
          if constexpr (EP == 0) {
            Cb[(size_t)r * ldc + cc] = (bf16)v;
          } else if constexpr (EP == 1) {
            float gt = gate ? gate[(size_t)(r >> 10) * 6912 + gate_off + cc] : 1.0f;
            float o = resid[(size_t)r * ldc + cc] + gt * v;
            Cf[(size_t)r * ldc + cc] = o;
            if (Cb2) Cb2[(size_t)r * ldc + cc] = (bf16)o;
          } else {
            float t = tanhf(0.7978845608028654f * (v + 0.044715f * v * v * v));
            Cb[(size_t)r * ldc + cc] = (bf16)(0.5f * v * (1.0f + t));
          }
        }
      }
}

// ---------------------------------------------------------------- flash attention (hd=72, pad 96)
// block = (b, h, 64 q rows); 4 waves x 16 rows; online softmax; swapped QK -> S^T.

__global__ __launch_bounds__(256) void attn_kernel(
    const bf16* __restrict__ Q, long q_b, int q_h_off, int q_ld,
    const bf16* __restrict__ K, long k_b, int k_h_off, int k_ld,
    const bf16* __restrict__ V, long v_b, int v_h_off, int v_ld,
    bf16* __restrict__ O, long o_b, int o_h_off, int o_ld,
    int Nk, float scale) {
  __shared__ __align__(16) bf16 lK[32 * 104];
  __shared__ __align__(16) bf16 lVT[80 * 40];
  int tid = threadIdx.x, lane = tid & 63, w = tid >> 6;
  int bz = blockIdx.z, hy = blockIdx.y;
  int q0 = blockIdx.x * 64;
  int g = lane >> 4, i16 = lane & 15;
  const bf16* Qb = Q + (long)bz * q_b + hy * q_h_off;
  const bf16* Kb = K + (long)bz * k_b + hy * k_h_off;
  const bf16* Vb = V + (long)bz * v_b + hy * v_h_off;
  int qr = q0 + w * 16 + i16;
  const bf16* qrow = Qb + (long)qr * q_ld;
  bf16x8 qf[3];
  qf[0] = *(const bf16x8*)(qrow + g * 8);
  qf[1] = *(const bf16x8*)(qrow + 32 + g * 8);
  if (g == 0) qf[2] = *(const bf16x8*)(qrow + 64);
  else { bf16x8 z = {}; qf[2] = z; }
  float m = -1e30f, l = 0.f;
  f32x4 ot[5] = {};
  for (int k0 = 0; k0 < Nk; k0 += 32) {
    __syncthreads();
    for (int idx = tid; idx < 32 * 48; idx += 256) {      // K tile [32][104], d zero-padded to 96
      int r = idx / 48, d = (idx % 48) * 2;
      int krow = k0 + r;
      uint32_t val = 0;
      if (krow < Nk && d < 72) val = *(const uint32_t*)(Kb + (long)krow * k_ld + d);
      *(uint32_t*)&lK[r * 104 + d] = val;
    }
    for (int idx = tid; idx < 32 * 40; idx += 256) {      // V^T tile [80][40]
      int r = idx / 40, d = (idx % 40) * 2;
      int vrow = k0 + r;
      uint32_t val = 0;
      if (vrow < Nk && d < 72) val = *(const uint32_t*)(Vb + (long)vrow * v_ld + d);
      lVT[d * 40 + r]       = __builtin_bit_cast(bf16, (unsigned short)(val & 0xffffu));
      lVT[(d + 1) * 40 + r] = __builtin_bit_cast(bf16, (unsigned short)(val >> 16));
    }
    __syncthreads();
    f32x4 sa = {}, sb = {};
    #pragma unroll
    for (int cD = 0; cD < 3; ++cD) {
      bf16x8 ka = *(const bf16x8*)&lK[i16 * 104 + cD * 32 + g * 8];
      bf16x8 kb = *(const bf16x8*)&lK[(16 + i16) * 104 + cD * 32 + g * 8];
      sa = __builtin_amdgcn_mfma_f32_16x16x32_bf16(ka, qf[cD], sa, 0, 0, 0);
      sb = __builtin_amdgcn_mfma_f32_16x16x32_bf16(kb, qf[cD], sb, 0, 0, 0);
    }
    float p[8];
    #pragma unroll
    for (int r = 0; r < 4; ++r) { p[r] = sa[r] * scale; p[4 + r] = sb[r] * scale; }
    if (k0 + 32 > Nk) {
      #pragma unroll
      for (int r = 0; r < 4; ++r) {
        if (k0 + g * 4 + r >= Nk)      p[r]     = -1e30f;
        if (k0 + 16 + g * 4 + r >= Nk) p[4 + r] = -1e30f;
      }
    }
    float tm = p[0];
    #pragma unroll
    for (int j = 1; j < 8; ++j) tm = fmaxf(tm, p[j]);
    tm = fmaxf(tm, __shfl_xor(tm, 16));
    tm = fmaxf(tm, __shfl_xor(tm, 32));
    float mnew = fmaxf(m, tm);
    float alpha = __expf(m - mnew);
    float psum = 0.f;
    #pragma unroll
    for (int j = 0; j < 8; ++j) { p[j] = __expf(p[j] - mnew); psum += p[j]; }
    psum += __shfl_xor(psum, 16);
    psum += __shfl_xor(psum, 32);
    l = l * alpha + psum;
    m = mnew;
    #pragma unroll
    for (int dt = 0; dt < 5; ++dt) ot[dt] *= alpha;
    // repack P^T (C-layout: key = 4g'+reg at lane(g',q)) into operand layout (key = 8g+i)
    uint32_t dA0 = pkbf(p[0], p[1]), dA1 = pkbf(p[2], p[3]);
    uint32_t dB0 = pkbf(p[4], p[5]), dB1 = pkbf(p[6], p[7]);
    int s0 = ((2 * g) & 3) * 16 + i16;
    int s1 = s0 + 16;
    uint32_t wa0 = (uint32_t)__shfl((int)dA0, s0), wa1 = (uint32_t)__shfl((int)dA1, s0);
    uint32_t wa2 = (uint32_t)__shfl((int)dA0, s1), wa3 = (uint32_t)__shfl((int)dA1, s1);
    uint32_t wb0 = (uint32_t)__shfl((int)dB0, s0), wb1 = (uint32_t)__shfl((int)dB1, s0);
    uint32_t wb2 = (uint32_t)__shfl((int)dB0, s1), wb3 = (uint32_t)__shfl((int)dB1, s1);
    U8 pu;
    pu.u[0] = g < 2 ? wa0 : wb0;
    pu.u[1] = g < 2 ? wa1 : wb1;
    pu.u[2] = g < 2 ? wa2 : wb2;
    pu.u[3] = g < 2 ? wa3 : wb3;
    #pragma unroll
    for (int dt = 0; dt < 5; ++dt) {
      bf16x8 vt = *(const bf16x8*)&lVT[(dt * 16 + i16) * 40 + g * 8];
      ot[dt] = __builtin_amdgcn_mfma_f32_16x16x32_bf16(vt, pu.v, ot[dt], 0, 0, 0);
    }
  }
  float inv = 1.0f / l;
  // BUGFIX (round 2): head offset must be hy * o_h_off (was missing hy ->
  // all 16 heads wrote head-1's slot and 15/16 of O was never written).
  bf16* orow = O + (long)bz * o_b + (long)hy * o_h_off + (long)(q0 + w * 16 + i16) * o_ld;
  #pragma unroll
  for (int dt = 0; dt < 5; ++dt)
    #pragma unroll
    for (int rg = 0; rg < 4; ++rg) {
      int d = dt * 16 + g * 4 + rg;
      if (d < 72) orow[d] = (bf16)(ot[dt][rg] * inv);
    }
}

// ---------------------------------------------------------------- launch

extern "C" void kernel_launch(void* const* d_in, const int* in_sizes, int n_in,
                              void* d_out, int out_size, void* d_ws, size_t ws_size,
                              hipStream_t stream) {
  (void)in_sizes; (void)n_in; (void)out_size; (void)ws_size;
  const float* x        = (const float*)d_in[0];
  const float* c        = (const float*)d_in[1];
  const float* t_emb    = (const float*)d_in[2];
  const float* qkv_w    = (const float*)d_in[3];
  const float* qkv_b    = (const float*)d_in[4];
  const float* proj_w   = (const float*)d_in[5];
  const float* proj_b   = (const float*)d_in[6];
  const float* to_q_w   = (const float*)d_in[7];
  const float* to_k_w   = (const float*)d_in[8];
  const float* to_v_w   = (const float*)d_in[9];
  const float* to_out_w = (const float*)d_in[10];
  const float* to_out_b = (const float*)d_in[11];
  const float* mlp_w1   = (const float*)d_in[12];
  const float* mlp_b1   = (const float*)d_in[13];
  const float* mlp_w2   = (const float*)d_in[14];
  const float* mlp_b2   = (const float*)d_in[15];
  const float* ada_w    = (const float*)d_in[16];
  const float* ada_b    = (const float*)d_in[17];
  float* out = (float*)d_out;

  char* ws = (char*)d_ws;
  size_t off = 0;
  auto alloc = [&](size_t b) { size_t o = off; off += (b + 255) & ~(size_t)255; return o; };
  bf16* wq    = (bf16*)(ws + alloc((size_t)3456 * 1152 * 2));
  bf16* wproj = (bf16*)(ws + alloc((size_t)1152 * 1152 * 2));
  bf16* wtoq  = (bf16*)(ws + alloc((size_t)1152 * 1152 * 2));
  bf16* wtok  = (bf16*)(ws + alloc((size_t)1152 * 768 * 2));
  bf16* wtov  = (bf16*)(ws + alloc((size_t)1152 * 768 * 2));
  bf16* wtoout= (bf16*)(ws + alloc((size_t)1152 * 1152 * 2));
  bf16* wm1   = (bf16*)(ws + alloc((size_t)4608 * 1152 * 2));
  bf16* wm2   = (bf16*)(ws + alloc((size_t)1152 * 4608 * 2));
  bf16* cb    = (bf16*)(ws + alloc((size_t)616 * 768 * 2));
  float* stl  = (float*)(ws + alloc((size_t)8 * 1152 * 4));
  float* modb = (float*)(ws + alloc((size_t)8 * 6912 * 4));
  bf16* S1    = (bf16*)(ws + alloc((size_t)8192 * 1152 * 2));   // h1 / x2b / h2
  bf16* R1    = (bf16*)(ws + alloc((size_t)8192 * 4608 * 2));   // qkv / q2,kc,vc / mid
  bf16* R2    = (bf16*)(ws + alloc((size_t)8192 * 1152 * 2));   // o / o2
  float* x2   = (float*)(ws + alloc((size_t)8192 * 1152 * 4));

  bf16* qkvbuf = R1;
  bf16* q2 = R1;
  bf16* kc = (bf16*)((char*)R1 + (size_t)8192 * 1152 * 2);
  bf16* vc = (bf16*)((char*)kc + (size_t)616 * 1152 * 2);
  bf16* mid = R1;

  auto cvt = [&](const float* src, bf16* dst, size_t n) {
    int n4 = (int)(n / 4);
    f2b_kernel<<<(n4 + 255) / 256, 256, 0, stream>>>(src, dst, n4);
  };
  cvt(qkv_w,    wq,    (size_t)3456 * 1152);
  cvt(proj_w,   wproj, (size_t)1152 * 1152);
  cvt(to_q_w,   wtoq,  (size_t)1152 * 1152);
  cvt(to_k_w,   wtok,  (size_t)1152 * 768);
  cvt(to_v_w,   wtov,  (size_t)1152 * 768);
  cvt(to_out_w, wtoout,(size_t)1152 * 1152);
  cvt(mlp_w1,   wm1,   (size_t)4608 * 1152);
  cvt(mlp_w2,   wm2,   (size_t)1152 * 4608);
  cvt(c,        cb,    (size_t)616 * 768);

  silu_kernel<<<36, 256, 0, stream>>>(t_emb, stl, 8 * 1152);
  mod_kernel<<<13824, 256, 0, stream>>>(stl, ada_w, ada_b, modb);

  // h1 = modulate(ln(x), sh_msa, sc_msa)
  ln_mod_kernel<<<8192, 256, 0, stream>>>(x, modb, 0, 1152, S1);

  // qkv
  gemm_bt<0><<<dim3(64, 27), 256, 0, stream>>>(S1, 1152, wq, 1152, qkv_b,
      qkvbuf, 3456, nullptr, nullptr, nullptr, 0, nullptr, 8192, 3456, 1152);

  const float scale = 0.11785113019775793f;  // 72^-0.5
  attn_kernel<<<dim3(16, 16, 8), 256, 0, stream>>>(
      qkvbuf,        (long)1024 * 3456, 72, 3456,
      qkvbuf + 1152, (long)1024 * 3456, 72, 3456,
      qkvbuf + 2304, (long)1024 * 3456, 72, 3456,
      R2,            (long)1024 * 1152, 72, 1152,
      1024, scale);

  // x2 = x + g_msa*(o@proj^T + b); also x2 as bf16 into S1
  gemm_bt<1><<<dim3(64, 9), 256, 0, stream>>>(R2, 1152, wproj, 1152, proj_b,
      nullptr, 1152, x2, x, modb, 2304, S1, 8192, 1152, 1152);

  // cross-attn projections
  gemm_bt<0><<<dim3(64, 9), 256, 0, stream>>>(S1, 1152, wtoq, 1152, nullptr,
      q2, 1152, nullptr, nullptr, nullptr, 0, nullptr, 8192, 1152, 1152);
  gemm_bt<0><<<dim3(5, 9), 256, 0, stream>>>(cb, 768, wtok, 768, nullptr,
      kc, 1152, nullptr, nullptr, nullptr, 0, nullptr, 616, 1152, 768);
  gemm_bt<0><<<dim3(5, 9), 256, 0, stream>>>(cb, 768, wtov, 768, nullptr,
      vc, 1152, nullptr, nullptr, nullptr, 0, nullptr, 616, 1152, 768);

  attn_kernel<<<dim3(16, 16, 8), 256, 0, stream>>>(
      q2, (long)1024 * 1152, 72, 1152,
      kc, (long)77 * 1152,   72, 1152,
      vc, (long)77 * 1152,   72, 1152,
      R2, (long)1024 * 1152, 72, 1152,
      77, scale);

  // x3 = x2 + (o2@to_out^T + b)  -> stored in d_out
  gemm_bt<1><<<dim3(64, 9), 256, 0, stream>>>(R2, 1152, wtoout, 1152, to_out_b,
      nullptr, 1152, out, x2, nullptr, 0, nullptr, 8192, 1152, 1152);

  // h2 = modulate(ln(x3), sh_mlp, sc_mlp)
  ln_mod_kernel<<<8192, 256, 0, stream>>>(out, modb, 3456, 4608, S1);

  // mid = gelu(h2@w1^T + b1)
  gemm_bt<2><<<dim3(64, 36), 256, 0, stream>>>(S1, 1152, wm1, 1152, mlp_b1,
      mid, 4608, nullptr, nullptr, nullptr, 0, nullptr, 8192, 4608, 1152);

  // out = x3 + g_mlp*(mid@w2^T + b2)
  gemm_bt<1><<<dim3(64, 9), 256, 0, stream>>>(mid, 4608, wm2, 4608, mlp_b2,
      nullptr, 1152, out, out, modb, 5760, nullptr, 8192, 1152, 4608);
}

// Round 7
// 1259.704 us; speedup vs baseline: 1.0896x; 1.0896x over previous
//
#include <hip/hip_runtime.h>
#include <stdint.h>

typedef __bf16 bf16;
typedef bf16 bf16x8 __attribute__((ext_vector_type(8)));
typedef bf16 bf16x4 __attribute__((ext_vector_type(4)));
typedef float f32x4 __attribute__((ext_vector_type(4)));

#define DEV __device__ __forceinline__

// ---------------------------------------------------------------- utilities

DEV void gload_lds16(const bf16* g, bf16* l) {
  __builtin_amdgcn_global_load_lds((const __attribute__((address_space(1))) void*)g,
                                   (__attribute__((address_space(3))) void*)l,
                                   16, 0, 0);
}

DEV uint32_t pkbf(float a, float b) {
  unsigned short ua = __builtin_bit_cast(unsigned short, (bf16)a);
  unsigned short ub = __builtin_bit_cast(unsigned short, (bf16)b);
  return (uint32_t)ua | ((uint32_t)ub << 16);
}

union U8 { uint32_t u[4]; bf16x8 v; };

// ---------------------------------------------------------------- f32 -> bf16

__global__ void f2b_kernel(const float* __restrict__ in, bf16* __restrict__ out, int n4) {
  int i = blockIdx.x * 256 + threadIdx.x;
  if (i < n4) {
    float4 v = ((const float4*)in)[i];
    bf16x4 o;
    o[0] = (bf16)v.x; o[1] = (bf16)v.y; o[2] = (bf16)v.z; o[3] = (bf16)v.w;
    *(bf16x4*)(out + (size_t)i * 4) = o;
  }
}

// ---------------------------------------------------------------- silu(t_emb)

__global__ void silu_kernel(const float* __restrict__ in, float* __restrict__ out, int n) {
  int i = blockIdx.x * 256 + threadIdx.x;
  if (i < n) { float v = in[i]; out[i] = v / (1.0f + __expf(-v)); }
}

// ---------------------------------------------------------------- mod = silu(t) @ ada_w^T + ada_b   [8,6912]

__global__ __launch_bounds__(256) void mod_kernel(
    const float* __restrict__ st, const float* __restrict__ ada_w,
    const float* __restrict__ ada_b, float* __restrict__ modout) {
  int gw = (blockIdx.x * 256 + threadIdx.x) >> 6;
  int lane = threadIdx.x & 63;
  if (gw >= 8 * 6912) return;
  int b = gw / 6912, j = gw % 6912;
  const float* sp = st + b * 1152;
  const float* wp = ada_w + (size_t)j * 1152;
  float acc = 0.f;
  for (int k = lane; k < 1152; k += 64) acc += sp[k] * wp[k];
  #pragma unroll
  for (int off = 32; off; off >>= 1) acc += __shfl_xor(acc, off);
  if (lane == 0) modout[(size_t)b * 6912 + j] = acc + ada_b[j];
}

// ---------------------------------------------------------------- LN + modulate -> bf16

__global__ __launch_bounds__(256) void ln_mod_kernel(
    const float* __restrict__ x, const float* __restrict__ mod,
    int sh_off, int sc_off, bf16* __restrict__ out) {
  int row = blockIdx.x, tid = threadIdx.x;
  int b = row >> 10;
  const float* xr = x + (size_t)row * 1152;
  float vals[5];
  float s = 0.f, s2 = 0.f;
  #pragma unroll
  for (int it = 0; it < 5; ++it) {
    int i = tid + it * 256;
    float v = (i < 1152) ? xr[i] : 0.f;
    vals[it] = v; s += v; s2 += v * v;
  }
  #pragma unroll
  for (int off = 32; off; off >>= 1) { s += __shfl_xor(s, off); s2 += __shfl_xor(s2, off); }
  __shared__ float rs[4], rs2[4];
  int w = tid >> 6, lane = tid & 63;
  if (lane == 0) { rs[w] = s; rs2[w] = s2; }
  __syncthreads();
  s = rs[0] + rs[1] + rs[2] + rs[3];
  s2 = rs2[0] + rs2[1] + rs2[2] + rs2[3];
  float mu = s * (1.0f / 1152.0f);
  float var = s2 * (1.0f / 1152.0f) - mu * mu;
  float rstd = rsqrtf(var + 1e-6f);
  const float* shp = mod + (size_t)b * 6912 + sh_off;
  const float* scp = mod + (size_t)b * 6912 + sc_off;
  #pragma unroll
  for (int it = 0; it < 5; ++it) {
    int i = tid + it * 256;
    if (i < 1152) {
      float v = (vals[it] - mu) * rstd;
      out[(size_t)row * 1152 + i] = (bf16)(v * (1.0f + scp[i]) + shp[i]);
    }
  }
}

// ---------------------------------------------------------------- GEMM  C = A @ W^T (+epilogues)
// A [M,K] bf16 row-major, W [N,K] bf16 row-major. 128x128 tile, BK=32, 4 waves.

DEV void stage_tile(const bf16* src, int ld, int row0, int maxrow, int k0,
                    bf16* lds, int tid) {
  int lane = tid & 63, wv = tid >> 6;
  #pragma unroll
  for (int j = 0; j < 2; ++j) {
    int r = j * 64 + wv * 16 + (lane >> 2);
    int kk = (lane & 3) * 8;
    int gr = min(row0 + r, maxrow);
    const bf16* g = src + (size_t)gr * ld + k0 + kk;
    bf16* l = lds + (j * 64 + wv * 16) * 32;   // wave-uniform base; HW adds lane*16B
    gload_lds16(g, l);
  }
}

// EP: 0 = bias -> bf16 Cb ; 1 = Cf = resid + gate*(acc+bias) (+opt bf16 Cb2) ; 2 = gelu -> bf16 Cb
template <int EP>
__global__ __launch_bounds__(256) void gemm_bt(
    const bf16* __restrict__ A, int lda,
    const bf16* __restrict__ W, int ldw,
    const float* __restrict__ bias,
    bf16* __restrict__ Cb, int ldc,
    float* __restrict__ Cf,
    const float* __restrict__ resid,
    const float* __restrict__ gate, int gate_off,
    bf16* __restrict__ Cb2,
    int M, int N, int K) {
  __shared__ __align__(16) bf16 lA[128 * 32];
  __shared__ __align__(16) bf16 lB[128 * 32];
  int tid = threadIdx.x, lane = tid & 63, w = tid >> 6;
  int wr = w >> 1, wc = w & 1;
  int row0 = blockIdx.x * 128, col0 = blockIdx.y * 128;
  f32x4 acc[4][4] = {};
  int nk = K >> 5;
  int rbase = wr * 64 + (lane & 15);
  int cbase = wc * 64 + (lane & 15);
  int koff = (lane >> 4) * 8;
  for (int ks = 0; ks < nk; ++ks) {
    stage_tile(A, lda, row0, M - 1, ks * 32, lA, tid);
    stage_tile(W, ldw, col0, N - 1, ks * 32, lB, tid);
    __syncthreads();           // drains vmcnt(0) for global_load_lds, then barrier
    bf16x8 af[4], bg[4];
    #pragma unroll
    for (int i = 0; i < 4; ++i) af[i] = *(const bf16x8*)&lA[(rbase + i * 16) * 32 + koff];
    #pragma unroll
    for (int i = 0; i < 4; ++i) bg[i] = *(const bf16x8*)&lB[(cbase + i * 16) * 32 + koff];
    #pragma unroll
    for (int mi = 0; mi < 4; ++mi)
      #pragma unroll
      for (int ni = 0; ni < 4; ++ni)
        acc[mi][ni] = __builtin_amdgcn_mfma_f32_16x16x32_bf16(af[mi], bg[ni], acc[mi][ni], 0, 0, 0);
    __syncthreads();
  }
  int r0 = row0 + wr * 64, c0 = col0 + wc * 64;
  #pragma unroll
  for (int mi = 0; mi < 4; ++mi)
    #pragma unroll
    for (int ni = 0; ni < 4; ++ni)
      #pragma unroll
      for (int rg = 0; rg < 4; ++rg) {
        int r = r0 + mi * 16 + (lane >> 4) * 4 + rg;
        int cc = c0 + ni * 16 + (lane & 15);
        if (r < M) {
          float v = acc[mi][ni][rg];
          if (bias) v += bias[cc];
          if constexpr (EP == 0) {
            Cb[(size_t)r * ldc + cc] = (bf16)v;
          } else if constexpr (EP == 1) {
            float gt = gate ? gate[(size_t)(r >> 10) * 6912 + gate_off + cc] : 1.0f;
            float o = resid[(size_t)r * ldc + cc] + gt * v;
            Cf[(size_t)r * ldc + cc] = o;
            if (Cb2) Cb2[(size_t)r * ldc + cc] = (bf16)o;
          } else {
            float t = tanhf(0.7978845608028654f * (v + 0.044715f * v * v * v));
            Cb[(size_t)r * ldc + cc] = (bf16)(0.5f * v * (1.0f + t));
          }
        }
      }
}

// ---------------------------------------------------------------- flash attention (hd=72, pad 96)
// block = (b, h, 256 q rows); 4 waves x (4 q-subtiles of 16 rows); online softmax;
// swapped QK -> S^T. K/V staging amortized 4x vs round-5 version; dwordx4 staging.

__global__ __launch_bounds__(256) void attn_kernel(
    const bf16* __restrict__ Q, long q_b, int q_h_off, int q_ld,
    const bf16* __restrict__ K, long k_b, int k_h_off, int k_ld,
    const bf16* __restrict__ V, long v_b, int v_h_off, int v_ld,
    bf16* __restrict__ O, long o_b, int o_h_off, int o_ld,
    int Nk, float scale) {
  __shared__ __align__(16) bf16 lK[32 * 104];   // [key r][d], d cols 72..103 zeroed once
  __shared__ __align__(16) bf16 lVT[80 * 40];   // [d][key r]; rows 72..79 stale (confined)
  int tid = threadIdx.x, lane = tid & 63, w = tid >> 6;
  int bz = blockIdx.z, hy = blockIdx.y;
  int q0 = blockIdx.x * 256;
  int g = lane >> 4, i16 = lane & 15;
  const bf16* Qb = Q + (long)bz * q_b + (long)hy * q_h_off;
  const bf16* Kb = K + (long)bz * k_b + (long)hy * k_h_off;
  const bf16* Vb = V + (long)bz * v_b + (long)hy * v_h_off;

  // Q fragments for 4 q-subtiles (row = q0 + w*64 + qp*16 + i16)
  bf16x8 qf[4][3];
  #pragma unroll
  for (int qp = 0; qp < 4; ++qp) {
    const bf16* qrow = Qb + (long)(q0 + w * 64 + qp * 16 + i16) * q_ld;
    qf[qp][0] = *(const bf16x8*)(qrow + g * 8);
    qf[qp][1] = *(const bf16x8*)(qrow + 32 + g * 8);
    if (g == 0) qf[qp][2] = *(const bf16x8*)(qrow + 64);
    else { bf16x8 z = {}; qf[qp][2] = z; }
  }

  // zero K padding cols 72..103 once (NaN-safety: they hit 0-valued Q k-slots)
  for (int i = tid; i < 512; i += 256) {
    int r = i >> 4, cu = i & 15;
    ((uint32_t*)lK)[r * 52 + 36 + cu] = 0;
  }

  float m[4], l[4];
  #pragma unroll
  for (int qp = 0; qp < 4; ++qp) { m[qp] = -1e30f; l[qp] = 0.f; }
  f32x4 ot[5][4] = {};

  for (int k0 = 0; k0 < Nk; k0 += 32) {
    __syncthreads();
    // stage K tile: 32 keys x 72 d, 9 dwordx4 chunks per key, rows padded to 104
    #pragma unroll
    for (int s = 0; s < 2; ++s) {
      int cidx = tid + s * 256;
      if (cidx < 288) {
        int r = cidx & 31, cch = cidx >> 5;
        int krow = k0 + r;
        uint4 val = {0, 0, 0, 0};
        if (krow < Nk) val = *(const uint4*)(Kb + (long)krow * k_ld + cch * 8);
        *(uint4*)&lK[r * 104 + cch * 8] = val;
      }
    }
    // stage V^T: lanes span consecutive keys -> LDS write banks ~conflict-free
    #pragma unroll
    for (int s = 0; s < 2; ++s) {
      int cidx = tid + s * 256;
      if (cidx < 288) {
        int r = cidx & 31, cch = cidx >> 5;
        int vrow = k0 + r;
        uint4 val = {0, 0, 0, 0};
        if (vrow < Nk) val = *(const uint4*)(Vb + (long)vrow * v_ld + cch * 8);
        uint32_t uu[4] = {val.x, val.y, val.z, val.w};
        #pragma unroll
        for (int j = 0; j < 4; ++j) {
          lVT[(cch * 8 + 2 * j) * 40 + r]     = __builtin_bit_cast(bf16, (unsigned short)(uu[j] & 0xffffu));
          lVT[(cch * 8 + 2 * j + 1) * 40 + r] = __builtin_bit_cast(bf16, (unsigned short)(uu[j] >> 16));
        }
      }
    }
    __syncthreads();

    // hoist K fragments (shared across the 4 q-subtiles)
    bf16x8 ka[3], kb[3];
    #pragma unroll
    for (int cD = 0; cD < 3; ++cD) {
      ka[cD] = *(const bf16x8*)&lK[i16 * 104 + cD * 32 + g * 8];
      kb[cD] = *(const bf16x8*)&lK[(16 + i16) * 104 + cD * 32 + g * 8];
    }

    bf16x8 pu[4];
    #pragma unroll
    for (int qp = 0; qp < 4; ++qp) {
      f32x4 sa = {}, sb = {};
      #pragma unroll
      for (int cD = 0; cD < 3; ++cD) {
        sa = __builtin_amdgcn_mfma_f32_16x16x32_bf16(ka[cD], qf[qp][cD], sa, 0, 0, 0);
        sb = __builtin_amdgcn_mfma_f32_16x16x32_bf16(kb[cD], qf[qp][cD], sb, 0, 0, 0);
      }
      float p[8];
      #pragma unroll
      for (int r = 0; r < 4; ++r) { p[r] = sa[r] * scale; p[4 + r] = sb[r] * scale; }
      if (k0 + 32 > Nk) {
        #pragma unroll
        for (int r = 0; r < 4; ++r) {
          if (k0 + g * 4 + r >= Nk)      p[r]     = -1e30f;
          if (k0 + 16 + g * 4 + r >= Nk) p[4 + r] = -1e30f;
        }
      }
      float tm = p[0];
      #pragma unroll
      for (int j = 1; j < 8; ++j) tm = fmaxf(tm, p[j]);
      tm = fmaxf(tm, __shfl_xor(tm, 16));
      tm = fmaxf(tm, __shfl_xor(tm, 32));
      float mnew = fmaxf(m[qp], tm);
      float alpha = __expf(m[qp] - mnew);
      float psum = 0.f;
      #pragma unroll
      for (int j = 0; j < 8; ++j) { p[j] = __expf(p[j] - mnew); psum += p[j]; }
      psum += __shfl_xor(psum, 16);
      psum += __shfl_xor(psum, 32);
      l[qp] = l[qp] * alpha + psum;
      m[qp] = mnew;
      #pragma unroll
      for (int dt = 0; dt < 5; ++dt) ot[dt][qp] *= alpha;
      // repack P^T (C-layout: key = 4g'+reg at lane(g',q)) into operand layout (key = 8g+i)
      uint32_t dA0 = pkbf(p[0], p[1]), dA1 = pkbf(p[2], p[3]);
      uint32_t dB0 = pkbf(p[4], p[5]), dB1 = pkbf(p[6], p[7]);
      int s0 = ((2 * g) & 3) * 16 + i16;
      int s1 = s0 + 16;
      uint32_t wa0 = (uint32_t)__shfl((int)dA0, s0), wa1 = (uint32_t)__shfl((int)dA1, s0);
      uint32_t wa2 = (uint32_t)__shfl((int)dA0, s1), wa3 = (uint32_t)__shfl((int)dA1, s1);
      uint32_t wb0 = (uint32_t)__shfl((int)dB0, s0), wb1 = (uint32_t)__shfl((int)dB1, s0);
      uint32_t wb2 = (uint32_t)__shfl((int)dB0, s1), wb3 = (uint32_t)__shfl((int)dB1, s1);
      U8 puu;
      puu.u[0] = g < 2 ? wa0 : wb0;
      puu.u[1] = g < 2 ? wa1 : wb1;
      puu.u[2] = g < 2 ? wa2 : wb2;
      puu.u[3] = g < 2 ? wa3 : wb3;
      pu[qp] = puu.v;
    }
    #pragma unroll
    for (int dt = 0; dt < 5; ++dt) {
      bf16x8 vt = *(const bf16x8*)&lVT[(dt * 16 + i16) * 40 + g * 8];
      #pragma unroll
      for (int qp = 0; qp < 4; ++qp)
        ot[dt][qp] = __builtin_amdgcn_mfma_f32_16x16x32_bf16(vt, pu[qp], ot[dt][qp], 0, 0, 0);
    }
  }
  #pragma unroll
  for (int qp = 0; qp < 4; ++qp) {
    float inv = 1.0f / l[qp];
    bf16* orow = O + (long)bz * o_b + (long)hy * o_h_off +
                 (long)(q0 + w * 64 + qp * 16 + i16) * o_ld;
    #pragma unroll
    for (int dt = 0; dt < 5; ++dt)
      #pragma unroll
      for (int rg = 0; rg < 4; ++rg) {
        int d = dt * 16 + g * 4 + rg;
        if (d < 72) orow[d] = (bf16)(ot[dt][qp][rg] * inv);
      }
  }
}

// ---------------------------------------------------------------- launch

extern "C" void kernel_launch(void* const* d_in, const int* in_sizes, int n_in,
                              void* d_out, int out_size, void* d_ws, size_t ws_size,
                              hipStream_t stream) {
  (void)in_sizes; (void)n_in; (void)out_size; (void)ws_size;
  const float* x        = (const float*)d_in[0];
  const float* c        = (const float*)d_in[1];
  const float* t_emb    = (const float*)d_in[2];
  const float* qkv_w    = (const float*)d_in[3];
  const float* qkv_b    = (const float*)d_in[4];
  const float* proj_w   = (const float*)d_in[5];
  const float* proj_b   = (const float*)d_in[6];
  const float* to_q_w   = (const float*)d_in[7];
  const float* to_k_w   = (const float*)d_in[8];
  const float* to_v_w   = (const float*)d_in[9];
  const float* to_out_w = (const float*)d_in[10];
  const float* to_out_b = (const float*)d_in[11];
  const float* mlp_w1   = (const float*)d_in[12];
  const float* mlp_b1   = (const float*)d_in[13];
  const float* mlp_w2   = (const float*)d_in[14];
  const float* mlp_b2   = (const float*)d_in[15];
  const float* ada_w    = (const float*)d_in[16];
  const float* ada_b    = (const float*)d_in[17];
  float* out = (float*)d_out;

  char* ws = (char*)d_ws;
  size_t off = 0;
  auto alloc = [&](size_t b) { size_t o = off; off += (b + 255) & ~(size_t)255; return o; };
  bf16* wq    = (bf16*)(ws + alloc((size_t)3456 * 1152 * 2));
  bf16* wproj = (bf16*)(ws + alloc((size_t)1152 * 1152 * 2));
  bf16* wtoq  = (bf16*)(ws + alloc((size_t)1152 * 1152 * 2));
  bf16* wtok  = (bf16*)(ws + alloc((size_t)1152 * 768 * 2));
  bf16* wtov  = (bf16*)(ws + alloc((size_t)1152 * 768 * 2));
  bf16* wtoout= (bf16*)(ws + alloc((size_t)1152 * 1152 * 2));
  bf16* wm1   = (bf16*)(ws + alloc((size_t)4608 * 1152 * 2));
  bf16* wm2   = (bf16*)(ws + alloc((size_t)1152 * 4608 * 2));
  bf16* cb    = (bf16*)(ws + alloc((size_t)616 * 768 * 2));
  float* stl  = (float*)(ws + alloc((size_t)8 * 1152 * 4));
  float* modb = (float*)(ws + alloc((size_t)8 * 6912 * 4));
  bf16* S1    = (bf16*)(ws + alloc((size_t)8192 * 1152 * 2));   // h1 / x2b / h2
  bf16* R1    = (bf16*)(ws + alloc((size_t)8192 * 4608 * 2));   // qkv / q2,kc,vc / mid
  bf16* R2    = (bf16*)(ws + alloc((size_t)8192 * 1152 * 2));   // o / o2
  float* x2   = (float*)(ws + alloc((size_t)8192 * 1152 * 4));

  bf16* qkvbuf = R1;
  bf16* q2 = R1;
  bf16* kc = (bf16*)((char*)R1 + (size_t)8192 * 1152 * 2);
  bf16* vc = (bf16*)((char*)kc + (size_t)616 * 1152 * 2);
  bf16* mid = R1;

  auto cvt = [&](const float* src, bf16* dst, size_t n) {
    int n4 = (int)(n / 4);
    f2b_kernel<<<(n4 + 255) / 256, 256, 0, stream>>>(src, dst, n4);
  };
  cvt(qkv_w,    wq,    (size_t)3456 * 1152);
  cvt(proj_w,   wproj, (size_t)1152 * 1152);
  cvt(to_q_w,   wtoq,  (size_t)1152 * 1152);
  cvt(to_k_w,   wtok,  (size_t)1152 * 768);
  cvt(to_v_w,   wtov,  (size_t)1152 * 768);
  cvt(to_out_w, wtoout,(size_t)1152 * 1152);
  cvt(mlp_w1,   wm1,   (size_t)4608 * 1152);
  cvt(mlp_w2,   wm2,   (size_t)1152 * 4608);
  cvt(c,        cb,    (size_t)616 * 768);

  silu_kernel<<<36, 256, 0, stream>>>(t_emb, stl, 8 * 1152);
  mod_kernel<<<13824, 256, 0, stream>>>(stl, ada_w, ada_b, modb);

  // h1 = modulate(ln(x), sh_msa, sc_msa)
  ln_mod_kernel<<<8192, 256, 0, stream>>>(x, modb, 0, 1152, S1);

  // qkv
  gemm_bt<0><<<dim3(64, 27), 256, 0, stream>>>(S1, 1152, wq, 1152, qkv_b,
      qkvbuf, 3456, nullptr, nullptr, nullptr, 0, nullptr, 8192, 3456, 1152);

  const float scale = 0.11785113019775793f;  // 72^-0.5
  attn_kernel<<<dim3(4, 16, 8), 256, 0, stream>>>(
      qkvbuf,        (long)1024 * 3456, 72, 3456,
      qkvbuf + 1152, (long)1024 * 3456, 72, 3456,
      qkvbuf + 2304, (long)1024 * 3456, 72, 3456,
      R2,            (long)1024 * 1152, 72, 1152,
      1024, scale);

  // x2 = x + g_msa*(o@proj^T + b); also x2 as bf16 into S1
  gemm_bt<1><<<dim3(64, 9), 256, 0, stream>>>(R2, 1152, wproj, 1152, proj_b,
      nullptr, 1152, x2, x, modb, 2304, S1, 8192, 1152, 1152);

  // cross-attn projections
  gemm_bt<0><<<dim3(64, 9), 256, 0, stream>>>(S1, 1152, wtoq, 1152, nullptr,
      q2, 1152, nullptr, nullptr, nullptr, 0, nullptr, 8192, 1152, 1152);
  gemm_bt<0><<<dim3(5, 9), 256, 0, stream>>>(cb, 768, wtok, 768, nullptr,
      kc, 1152, nullptr, nullptr, nullptr, 0, nullptr, 616, 1152, 768);
  gemm_bt<0><<<dim3(5, 9), 256, 0, stream>>>(cb, 768, wtov, 768, nullptr,
      vc, 1152, nullptr, nullptr, nullptr, 0, nullptr, 616, 1152, 768);

  attn_kernel<<<dim3(4, 16, 8), 256, 0, stream>>>(
      q2, (long)1024 * 1152, 72, 1152,
      kc, (long)77 * 1152,   72, 1152,
      vc, (long)77 * 1152,   72, 1152,
      R2, (long)1024 * 1152, 72, 1152,
      77, scale);

  // x3 = x2 + (o2@to_out^T + b)  -> stored in d_out
  gemm_bt<1><<<dim3(64, 9), 256, 0, stream>>>(R2, 1152, wtoout, 1152, to_out_b,
      nullptr, 1152, out, x2, nullptr, 0, nullptr, 8192, 1152, 1152);

  // h2 = modulate(ln(x3), sh_mlp, sc_mlp)
  ln_mod_kernel<<<8192, 256, 0, stream>>>(out, modb, 3456, 4608, S1);

  // mid = gelu(h2@w1^T + b1)
  gemm_bt<2><<<dim3(64, 36), 256, 0, stream>>>(S1, 1152, wm1, 1152, mlp_b1,
      mid, 4608, nullptr, nullptr, nullptr, 0, nullptr, 8192, 4608, 1152);

  // out = x3 + g_mlp*(mid@w2^T + b2)
  gemm_bt<1><<<dim3(64, 9), 256, 0, stream>>>(mid, 4608, wm2, 4608, mlp_b2,
      nullptr, 1152, out, out, modb, 5760, nullptr, 8192, 1152, 4608);
}

// Round 8
// 1223.007 us; speedup vs baseline: 1.1222x; 1.0300x over previous
//
#include <hip/hip_runtime.h>
#include <stdint.h>

typedef __bf16 bf16;
typedef bf16 bf16x8 __attribute__((ext_vector_type(8)));
typedef bf16 bf16x4 __attribute__((ext_vector_type(4)));
typedef float f32x4 __attribute__((ext_vector_type(4)));

#define DEV __device__ __forceinline__

// ---------------------------------------------------------------- utilities

DEV void gload_lds16(const bf16* g, bf16* l) {
  __builtin_amdgcn_global_load_lds((const __attribute__((address_space(1))) void*)g,
                                   (__attribute__((address_space(3))) void*)l,
                                   16, 0, 0);
}

DEV uint32_t pkbf(float a, float b) {
  unsigned short ua = __builtin_bit_cast(unsigned short, (bf16)a);
  unsigned short ub = __builtin_bit_cast(unsigned short, (bf16)b);
  return (uint32_t)ua | ((uint32_t)ub << 16);
}

union U8 { uint32_t u[4]; bf16x8 v; };

// ---------------------------------------------------------------- f32 -> bf16

__global__ void f2b_kernel(const float* __restrict__ in, bf16* __restrict__ out, int n4) {
  int i = blockIdx.x * 256 + threadIdx.x;
  if (i < n4) {
    float4 v = ((const float4*)in)[i];
    bf16x4 o;
    o[0] = (bf16)v.x; o[1] = (bf16)v.y; o[2] = (bf16)v.z; o[3] = (bf16)v.w;
    *(bf16x4*)(out + (size_t)i * 4) = o;
  }
}

// ---------------------------------------------------------------- silu(t_emb)

__global__ void silu_kernel(const float* __restrict__ in, float* __restrict__ out, int n) {
  int i = blockIdx.x * 256 + threadIdx.x;
  if (i < n) { float v = in[i]; out[i] = v / (1.0f + __expf(-v)); }
}

// ---------------------------------------------------------------- mod = silu(t) @ ada_w^T + ada_b   [8,6912]

__global__ __launch_bounds__(256) void mod_kernel(
    const float* __restrict__ st, const float* __restrict__ ada_w,
    const float* __restrict__ ada_b, float* __restrict__ modout) {
  int gw = (blockIdx.x * 256 + threadIdx.x) >> 6;
  int lane = threadIdx.x & 63;
  if (gw >= 8 * 6912) return;
  int b = gw / 6912, j = gw % 6912;
  const float* sp = st + b * 1152;
  const float* wp = ada_w + (size_t)j * 1152;
  float acc = 0.f;
  for (int k = lane; k < 1152; k += 64) acc += sp[k] * wp[k];
  #pragma unroll
  for (int off = 32; off; off >>= 1) acc += __shfl_xor(acc, off);
  if (lane == 0) modout[(size_t)b * 6912 + j] = acc + ada_b[j];
}

// ---------------------------------------------------------------- LN + modulate -> bf16

__global__ __launch_bounds__(256) void ln_mod_kernel(
    const float* __restrict__ x, const float* __restrict__ mod,
    int sh_off, int sc_off, bf16* __restrict__ out) {
  int row = blockIdx.x, tid = threadIdx.x;
  int b = row >> 10;
  const float* xr = x + (size_t)row * 1152;
  float vals[5];
  float s = 0.f, s2 = 0.f;
  #pragma unroll
  for (int it = 0; it < 5; ++it) {
    int i = tid + it * 256;
    float v = (i < 1152) ? xr[i] : 0.f;
    vals[it] = v; s += v; s2 += v * v;
  }
  #pragma unroll
  for (int off = 32; off; off >>= 1) { s += __shfl_xor(s, off); s2 += __shfl_xor(s2, off); }
  __shared__ float rs[4], rs2[4];
  int w = tid >> 6, lane = tid & 63;
  if (lane == 0) { rs[w] = s; rs2[w] = s2; }
  __syncthreads();
  s = rs[0] + rs[1] + rs[2] + rs[3];
  s2 = rs2[0] + rs2[1] + rs2[2] + rs2[3];
  float mu = s * (1.0f / 1152.0f);
  float var = s2 * (1.0f / 1152.0f) - mu * mu;
  float rstd = rsqrtf(var + 1e-6f);
  const float* shp = mod + (size_t)b * 6912 + sh_off;
  const float* scp = mod + (size_t)b * 6912 + sc_off;
  #pragma unroll
  for (int it = 0; it < 5; ++it) {
    int i = tid + it * 256;
    if (i < 1152) {
      float v = (vals[it] - mu) * rstd;
      out[(size_t)row * 1152 + i] = (bf16)(v * (1.0f + scp[i]) + shp[i]);
    }
  }
}

// ---------------------------------------------------------------- GEMM  C = A @ W^T (+epilogues)
// A [M,K] bf16 row-major, W [N,K] bf16 row-major. 128x128 tile, BK=32, 4 waves.

DEV void stage_tile(const bf16* src, int ld, int row0, int maxrow, int k0,
                    bf16* lds, int tid) {
  int lane = tid & 63, wv = tid >> 6;
  #pragma unroll
  for (int j = 0; j < 2; ++j) {
    int r = j * 64 + wv * 16 + (lane >> 2);
    int kk = (lane & 3) * 8;
    int gr = min(row0 + r, maxrow);
    const bf16* g = src + (size_t)gr * ld + k0 + kk;
    bf16* l = lds + (j * 64 + wv * 16) * 32;   // wave-uniform base; HW adds lane*16B
    gload_lds16(g, l);
  }
}

// EP: 0 = bias -> bf16 Cb ; 1 = Cf = resid + gate*(acc+bias) (+opt bf16 Cb2) ; 2 = gelu -> bf16 Cb
template <int EP>
__global__ __launch_bounds__(256) void gemm_bt(
    const bf16* __restrict__ A, int lda,
    const bf16* __restrict__ W, int ldw,
    const float* __restrict__ bias,
    bf16* __restrict__ Cb, int ldc,
    float* __restrict__ Cf,
    const float* __restrict__ resid,
    const float* __restrict__ gate, int gate_off,
    bf16* __restrict__ Cb2,
    int M, int N, int K) {
  __shared__ __align__(16) bf16 lA[128 * 32];
  __shared__ __align__(16) bf16 lB[128 * 32];
  int tid = threadIdx.x, lane = tid & 63, w = tid >> 6;
  int wr = w >> 1, wc = w & 1;
  int row0 = blockIdx.x * 128, col0 = blockIdx.y * 128;
  f32x4 acc[4][4] = {};
  int nk = K >> 5;
  int rbase = wr * 64 + (lane & 15);
  int cbase = wc * 64 + (lane & 15);
  int koff = (lane >> 4) * 8;
  for (int ks = 0; ks < nk; ++ks) {
    stage_tile(A, lda, row0, M - 1, ks * 32, lA, tid);
    stage_tile(W, ldw, col0, N - 1, ks * 32, lB, tid);
    __syncthreads();           // drains vmcnt(0) for global_load_lds, then barrier
    bf16x8 af[4], bg[4];
    #pragma unroll
    for (int i = 0; i < 4; ++i) af[i] = *(const bf16x8*)&lA[(rbase + i * 16) * 32 + koff];
    #pragma unroll
    for (int i = 0; i < 4; ++i) bg[i] = *(const bf16x8*)&lB[(cbase + i * 16) * 32 + koff];
    #pragma unroll
    for (int mi = 0; mi < 4; ++mi)
      #pragma unroll
      for (int ni = 0; ni < 4; ++ni)
        acc[mi][ni] = __builtin_amdgcn_mfma_f32_16x16x32_bf16(af[mi], bg[ni], acc[mi][ni], 0, 0, 0);
    __syncthreads();
  }
  int r0 = row0 + wr * 64, c0 = col0 + wc * 64;
  #pragma unroll
  for (int mi = 0; mi < 4; ++mi)
    #pragma unroll
    for (int ni = 0; ni < 4; ++ni)
      #pragma unroll
      for (int rg = 0; rg < 4; ++rg) {
        int r = r0 + mi * 16 + (lane >> 4) * 4 + rg;
        int cc = c0 + ni * 16 + (lane & 15);
        if (r < M) {
          float v = acc[mi][ni][rg];
          if (bias) v += bias[cc];
          if constexpr (EP == 0) {
            Cb[(size_t)r * ldc + cc] = (bf16)v;
          } else if constexpr (EP == 1) {
            float gt = gate ? gate[(size_t)(r >> 10) * 6912 + gate_off + cc] : 1.0f;
            float o = resid[(size_t)r * ldc + cc] + gt * v;
            Cf[(size_t)r * ldc + cc] = o;
            if (Cb2) Cb2[(size_t)r * ldc + cc] = (bf16)o;
          } else {
            float t = tanhf(0.7978845608028654f * (v + 0.044715f * v * v * v));
            Cb[(size_t)r * ldc + cc] = (bf16)(0.5f * v * (1.0f + t));
          }
        }
      }
}

// ---------------------------------------------------------------- flash attention (hd=72, pad 96)
// block = (b, h, 256 q rows); 4 waves x (4 q-subtiles of 16 rows); online softmax
// in exp2 domain with defer-max (THR); swapped QK -> S^T.
// Round-8: double-buffered LDS, async reg-staging (issue loads before compute,
// write after), 1 barrier/tile (was 2), V staged as packed u32 key-pairs.

__global__ __launch_bounds__(256) void attn_kernel(
    const bf16* __restrict__ Q, long q_b, int q_h_off, int q_ld,
    const bf16* __restrict__ K, long k_b, int k_h_off, int k_ld,
    const bf16* __restrict__ V, long v_b, int v_h_off, int v_ld,
    bf16* __restrict__ O, long o_b, int o_h_off, int o_ld,
    int Nk, float scale2) {           // scale2 = scale * log2(e); softmax in exp2 domain
  __shared__ __align__(16) bf16 lK[2][32 * 104];   // [buf][key r][d], cols 72..103 zeroed once
  __shared__ __align__(16) bf16 lVT[2][80 * 40];   // [buf][d][key]; rows 72..79 stale (confined)
  const float THR = 11.5424f;   // 8 nats in log2 units
  int tid = threadIdx.x, lane = tid & 63, w = tid >> 6;
  int bz = blockIdx.z, hy = blockIdx.y;
  int q0 = blockIdx.x * 256;
  int g = lane >> 4, i16 = lane & 15;
  const bf16* Qb = Q + (long)bz * q_b + (long)hy * q_h_off;
  const bf16* Kb = K + (long)bz * k_b + (long)hy * k_h_off;
  const bf16* Vb = V + (long)bz * v_b + (long)hy * v_h_off;

  // Q fragments for 4 q-subtiles (row = q0 + w*64 + qp*16 + i16)
  bf16x8 qf[4][3];
  #pragma unroll
  for (int qp = 0; qp < 4; ++qp) {
    const bf16* qrow = Qb + (long)(q0 + w * 64 + qp * 16 + i16) * q_ld;
    qf[qp][0] = *(const bf16x8*)(qrow + g * 8);
    qf[qp][1] = *(const bf16x8*)(qrow + 32 + g * 8);
    if (g == 0) qf[qp][2] = *(const bf16x8*)(qrow + 64);
    else { bf16x8 z = {}; qf[qp][2] = z; }
  }

  // zero K padding cols 72..103 in BOTH buffers once
  for (int i = tid; i < 1024; i += 256) {
    int b = i >> 9, r = (i >> 4) & 31, cu = i & 15;
    ((uint32_t*)lK[b])[r * 52 + 36 + cu] = 0;
  }

  // staging thread roles
  int kr = tid & 31, kch = tid >> 5;            // K chunk (row, 8-col chunk 0..7)
  int vrp = tid & 15, vch = tid >> 4;           // V pair (key-pair 0..15, chunk 0..8), tid<144

  uint4 rk0, rk1, rv0, rv1;
  int nt = (Nk + 31) >> 5;

  // ---- prologue: load tile 0 -> regs -> buf0
  {
    int k0 = 0;
    uint4 z = {0, 0, 0, 0};
    rk0 = z; rk1 = z; rv0 = z; rv1 = z;
    int krow = k0 + kr;
    if (krow < Nk) rk0 = *(const uint4*)(Kb + (long)krow * k_ld + kch * 8);
    if (tid < 32 && (k0 + tid) < Nk) rk1 = *(const uint4*)(Kb + (long)(k0 + tid) * k_ld + 64);
    if (tid < 144) {
      int r0 = k0 + 2 * vrp, r1 = r0 + 1;
      if (r0 < Nk) rv0 = *(const uint4*)(Vb + (long)r0 * v_ld + vch * 8);
      if (r1 < Nk) rv1 = *(const uint4*)(Vb + (long)r1 * v_ld + vch * 8);
    }
    *(uint4*)&lK[0][kr * 104 + kch * 8] = rk0;
    if (tid < 32) *(uint4*)&lK[0][tid * 104 + 64] = rk1;
    if (tid < 144) {
      uint32_t a[4] = {rv0.x, rv0.y, rv0.z, rv0.w};
      uint32_t b[4] = {rv1.x, rv1.y, rv1.z, rv1.w};
      uint32_t* wv = (uint32_t*)&lVT[0][0];
      #pragma unroll
      for (int j = 0; j < 8; ++j) {
        uint32_t lo = (a[j >> 1] >> ((j & 1) * 16)) & 0xffffu;
        uint32_t hi = (b[j >> 1] >> ((j & 1) * 16)) & 0xffffu;
        wv[(vch * 8 + j) * 20 + vrp] = lo | (hi << 16);
      }
    }
  }
  __syncthreads();

  float m[4], l[4];
  #pragma unroll
  for (int qp = 0; qp < 4; ++qp) { m[qp] = -1e30f; l[qp] = 0.f; }
  f32x4 ot[5][4] = {};

  int cur = 0;
  for (int t = 0; t < nt; ++t) {
    int nxt = t + 1;
    // ---- issue next-tile loads early (latency hides under compute)
    if (nxt < nt) {
      int k0 = nxt * 32;
      uint4 z = {0, 0, 0, 0};
      rk0 = z; rk1 = z; rv0 = z; rv1 = z;
      int krow = k0 + kr;
      if (krow < Nk) rk0 = *(const uint4*)(Kb + (long)krow * k_ld + kch * 8);
      if (tid < 32 && (k0 + tid) < Nk) rk1 = *(const uint4*)(Kb + (long)(k0 + tid) * k_ld + 64);
      if (tid < 144) {
        int r0 = k0 + 2 * vrp, r1 = r0 + 1;
        if (r0 < Nk) rv0 = *(const uint4*)(Vb + (long)r0 * v_ld + vch * 8);
        if (r1 < Nk) rv1 = *(const uint4*)(Vb + (long)r1 * v_ld + vch * 8);
      }
    }

    // ---- compute on buf[cur]
    const bf16* lKc = lK[cur];
    const bf16* lVc = lVT[cur];
    int k0 = t * 32;

    bf16x8 ka[3], kb[3];
    #pragma unroll
    for (int cD = 0; cD < 3; ++cD) {
      ka[cD] = *(const bf16x8*)&lKc[i16 * 104 + cD * 32 + g * 8];
      kb[cD] = *(const bf16x8*)&lKc[(16 + i16) * 104 + cD * 32 + g * 8];
    }

    bf16x8 pu[4];
    #pragma unroll
    for (int qp = 0; qp < 4; ++qp) {
      f32x4 sa = {}, sb = {};
      #pragma unroll
      for (int cD = 0; cD < 3; ++cD) {
        sa = __builtin_amdgcn_mfma_f32_16x16x32_bf16(ka[cD], qf[qp][cD], sa, 0, 0, 0);
        sb = __builtin_amdgcn_mfma_f32_16x16x32_bf16(kb[cD], qf[qp][cD], sb, 0, 0, 0);
      }
      float p[8];
      #pragma unroll
      for (int r = 0; r < 4; ++r) { p[r] = sa[r] * scale2; p[4 + r] = sb[r] * scale2; }
      if (k0 + 32 > Nk) {
        #pragma unroll
        for (int r = 0; r < 4; ++r) {
          if (k0 + g * 4 + r >= Nk)      p[r]     = -1e30f;
          if (k0 + 16 + g * 4 + r >= Nk) p[4 + r] = -1e30f;
        }
      }
      float tm = p[0];
      #pragma unroll
      for (int j = 1; j < 8; ++j) tm = fmaxf(tm, p[j]);
      tm = fmaxf(tm, __shfl_xor(tm, 16));
      tm = fmaxf(tm, __shfl_xor(tm, 32));
      // defer-max: only advance m when growth exceeds THR (skips O-rescale)
      float dlt = tm - m[qp];
      float alpha = 1.0f;
      if (dlt > THR) { alpha = exp2f(-dlt); m[qp] = tm; }
      float mq = m[qp];
      float psum = 0.f;
      #pragma unroll
      for (int j = 0; j < 8; ++j) { p[j] = exp2f(p[j] - mq); psum += p[j]; }
      psum += __shfl_xor(psum, 16);
      psum += __shfl_xor(psum, 32);
      l[qp] = l[qp] * alpha + psum;
      if (__any(alpha != 1.0f)) {
        #pragma unroll
        for (int dt = 0; dt < 5; ++dt) ot[dt][qp] *= alpha;
      }
      // repack P^T (C-layout: key = 4g'+reg at lane(g',q)) into operand layout (key = 8g+i)
      uint32_t dA0 = pkbf(p[0], p[1]), dA1 = pkbf(p[2], p[3]);
      uint32_t dB0 = pkbf(p[4], p[5]), dB1 = pkbf(p[6], p[7]);
      int s0 = ((2 * g) & 3) * 16 + i16;
      int s1 = s0 + 16;
      uint32_t wa0 = (uint32_t)__shfl((int)dA0, s0), wa1 = (uint32_t)__shfl((int)dA1, s0);
      uint32_t wa2 = (uint32_t)__shfl((int)dA0, s1), wa3 = (uint32_t)__shfl((int)dA1, s1);
      uint32_t wb0 = (uint32_t)__shfl((int)dB0, s0), wb1 = (uint32_t)__shfl((int)dB1, s0);
      uint32_t wb2 = (uint32_t)__shfl((int)dB0, s1), wb3 = (uint32_t)__shfl((int)dB1, s1);
      U8 puu;
      puu.u[0] = g < 2 ? wa0 : wb0;
      puu.u[1] = g < 2 ? wa1 : wb1;
      puu.u[2] = g < 2 ? wa2 : wb2;
      puu.u[3] = g < 2 ? wa3 : wb3;
      pu[qp] = puu.v;
    }
    #pragma unroll
    for (int dt = 0; dt < 5; ++dt) {
      bf16x8 vt = *(const bf16x8*)&lVc[(dt * 16 + i16) * 40 + g * 8];
      #pragma unroll
      for (int qp = 0; qp < 4; ++qp)
        ot[dt][qp] = __builtin_amdgcn_mfma_f32_16x16x32_bf16(vt, pu[qp], ot[dt][qp], 0, 0, 0);
    }

    // ---- write next tile into the other buffer; single barrier per tile
    if (nxt < nt) {
      int nb = cur ^ 1;
      *(uint4*)&lK[nb][kr * 104 + kch * 8] = rk0;
      if (tid < 32) *(uint4*)&lK[nb][tid * 104 + 64] = rk1;
      if (tid < 144) {
        uint32_t a[4] = {rv0.x, rv0.y, rv0.z, rv0.w};
        uint32_t b[4] = {rv1.x, rv1.y, rv1.z, rv1.w};
        uint32_t* wv = (uint32_t*)&lVT[nb][0];
        #pragma unroll
        for (int j = 0; j < 8; ++j) {
          uint32_t lo = (a[j >> 1] >> ((j & 1) * 16)) & 0xffffu;
          uint32_t hi = (b[j >> 1] >> ((j & 1) * 16)) & 0xffffu;
          wv[(vch * 8 + j) * 20 + vrp] = lo | (hi << 16);
        }
      }
      __syncthreads();
      cur = nb;
    }
  }

  #pragma unroll
  for (int qp = 0; qp < 4; ++qp) {
    float inv = 1.0f / l[qp];
    // head offset must include hy (round-2 bugfix)
    bf16* orow = O + (long)bz * o_b + (long)hy * o_h_off +
                 (long)(q0 + w * 64 + qp * 16 + i16) * o_ld;
    #pragma unroll
    for (int dt = 0; dt < 5; ++dt)
      #pragma unroll
      for (int rg = 0; rg < 4; ++rg) {
        int d = dt * 16 + g * 4 + rg;
        if (d < 72) orow[d] = (bf16)(ot[dt][qp][rg] * inv);
      }
  }
}

// ---------------------------------------------------------------- launch

extern "C" void kernel_launch(void* const* d_in, const int* in_sizes, int n_in,
                              void* d_out, int out_size, void* d_ws, size_t ws_size,
                              hipStream_t stream) {
  (void)in_sizes; (void)n_in; (void)out_size; (void)ws_size;
  const float* x        = (const float*)d_in[0];
  const float* c        = (const float*)d_in[1];
  const float* t_emb    = (const float*)d_in[2];
  const float* qkv_w    = (const float*)d_in[3];
  const float* qkv_b    = (const float*)d_in[4];
  const float* proj_w   = (const float*)d_in[5];
  const float* proj_b   = (const float*)d_in[6];
  const float* to_q_w   = (const float*)d_in[7];
  const float* to_k_w   = (const float*)d_in[8];
  const float* to_v_w   = (const float*)d_in[9];
  const float* to_out_w = (const float*)d_in[10];
  const float* to_out_b = (const float*)d_in[11];
  const float* mlp_w1   = (const float*)d_in[12];
  const float* mlp_b1   = (const float*)d_in[13];
  const float* mlp_w2   = (const float*)d_in[14];
  const float* mlp_b2   = (const float*)d_in[15];
  const float* ada_w    = (const float*)d_in[16];
  const float* ada_b    = (const float*)d_in[17];
  float* out = (float*)d_out;

  char* ws = (char*)d_ws;
  size_t off = 0;
  auto alloc = [&](size_t b) { size_t o = off; off += (b + 255) & ~(size_t)255; return o; };
  bf16* wq    = (bf16*)(ws + alloc((size_t)3456 * 1152 * 2));
  bf16* wproj = (bf16*)(ws + alloc((size_t)1152 * 1152 * 2));
  bf16* wtoq  = (bf16*)(ws + alloc((size_t)1152 * 1152 * 2));
  bf16* wtok  = (bf16*)(ws + alloc((size_t)1152 * 768 * 2));
  bf16* wtov  = (bf16*)(ws + alloc((size_t)1152 * 768 * 2));
  bf16* wtoout= (bf16*)(ws + alloc((size_t)1152 * 1152 * 2));
  bf16* wm1   = (bf16*)(ws + alloc((size_t)4608 * 1152 * 2));
  bf16* wm2   = (bf16*)(ws + alloc((size_t)1152 * 4608 * 2));
  bf16* cb    = (bf16*)(ws + alloc((size_t)616 * 768 * 2));
  float* stl  = (float*)(ws + alloc((size_t)8 * 1152 * 4));
  float* modb = (float*)(ws + alloc((size_t)8 * 6912 * 4));
  bf16* S1    = (bf16*)(ws + alloc((size_t)8192 * 1152 * 2));   // h1 / x2b / h2
  bf16* R1    = (bf16*)(ws + alloc((size_t)8192 * 4608 * 2));   // qkv / q2,kc,vc / mid
  bf16* R2    = (bf16*)(ws + alloc((size_t)8192 * 1152 * 2));   // o / o2
  float* x2   = (float*)(ws + alloc((size_t)8192 * 1152 * 4));

  bf16* qkvbuf = R1;
  bf16* q2 = R1;
  bf16* kc = (bf16*)((char*)R1 + (size_t)8192 * 1152 * 2);
  bf16* vc = (bf16*)((char*)kc + (size_t)616 * 1152 * 2);
  bf16* mid = R1;

  auto cvt = [&](const float* src, bf16* dst, size_t n) {
    int n4 = (int)(n / 4);
    f2b_kernel<<<(n4 + 255) / 256, 256, 0, stream>>>(src, dst, n4);
  };
  cvt(qkv_w,    wq,    (size_t)3456 * 1152);
  cvt(proj_w,   wproj, (size_t)1152 * 1152);
  cvt(to_q_w,   wtoq,  (size_t)1152 * 1152);
  cvt(to_k_w,   wtok,  (size_t)1152 * 768);
  cvt(to_v_w,   wtov,  (size_t)1152 * 768);
  cvt(to_out_w, wtoout,(size_t)1152 * 1152);
  cvt(mlp_w1,   wm1,   (size_t)4608 * 1152);
  cvt(mlp_w2,   wm2,   (size_t)1152 * 4608);
  cvt(c,        cb,    (size_t)616 * 768);

  silu_kernel<<<36, 256, 0, stream>>>(t_emb, stl, 8 * 1152);
  mod_kernel<<<13824, 256, 0, stream>>>(stl, ada_w, ada_b, modb);

  // h1 = modulate(ln(x), sh_msa, sc_msa)
  ln_mod_kernel<<<8192, 256, 0, stream>>>(x, modb, 0, 1152, S1);

  // qkv
  gemm_bt<0><<<dim3(64, 27), 256, 0, stream>>>(S1, 1152, wq, 1152, qkv_b,
      qkvbuf, 3456, nullptr, nullptr, nullptr, 0, nullptr, 8192, 3456, 1152);

  const float scale2 = 0.11785113019775793f * 1.4426950408889634f;  // 72^-0.5 * log2(e)
  attn_kernel<<<dim3(4, 16, 8), 256, 0, stream>>>(
      qkvbuf,        (long)1024 * 3456, 72, 3456,
      qkvbuf + 1152, (long)1024 * 3456, 72, 3456,
      qkvbuf + 2304, (long)1024 * 3456, 72, 3456,
      R2,            (long)1024 * 1152, 72, 1152,
      1024, scale2);

  // x2 = x + g_msa*(o@proj^T + b); also x2 as bf16 into S1
  gemm_bt<1><<<dim3(64, 9), 256, 0, stream>>>(R2, 1152, wproj, 1152, proj_b,
      nullptr, 1152, x2, x, modb, 2304, S1, 8192, 1152, 1152);

  // cross-attn projections
  gemm_bt<0><<<dim3(64, 9), 256, 0, stream>>>(S1, 1152, wtoq, 1152, nullptr,
      q2, 1152, nullptr, nullptr, nullptr, 0, nullptr, 8192, 1152, 1152);
  gemm_bt<0><<<dim3(5, 9), 256, 0, stream>>>(cb, 768, wtok, 768, nullptr,
      kc, 1152, nullptr, nullptr, nullptr, 0, nullptr, 616, 1152, 768);
  gemm_bt<0><<<dim3(5, 9), 256, 0, stream>>>(cb, 768, wtov, 768, nullptr,
      vc, 1152, nullptr, nullptr, nullptr, 0, nullptr, 616, 1152, 768);

  attn_kernel<<<dim3(4, 16, 8), 256, 0, stream>>>(
      q2, (long)1024 * 1152, 72, 1152,
      kc, (long)77 * 1152,   72, 1152,
      vc, (long)77 * 1152,   72, 1152,
      R2, (long)1024 * 1152, 72, 1152,
      77, scale2);

  // x3 = x2 + (o2@to_out^T + b)  -> stored in d_out
  gemm_bt<1><<<dim3(64, 9), 256, 0, stream>>>(R2, 1152, wtoout, 1152, to_out_b,
      nullptr, 1152, out, x2, nullptr, 0, nullptr, 8192, 1152, 1152);

  // h2 = modulate(ln(x3), sh_mlp, sc_mlp)
  ln_mod_kernel<<<8192, 256, 0, stream>>>(out, modb, 3456, 4608, S1);

  // mid = gelu(h2@w1^T + b1)
  gemm_bt<2><<<dim3(64, 36), 256, 0, stream>>>(S1, 1152, wm1, 1152, mlp_b1,
      mid, 4608, nullptr, nullptr, nullptr, 0, nullptr, 8192, 4608, 1152);

  // out = x3 + g_mlp*(mid@w2^T + b2)
  gemm_bt<1><<<dim3(64, 9), 256, 0, stream>>>(mid, 4608, wm2, 4608, mlp_b2,
      nullptr, 1152, out, out, modb, 5760, nullptr, 8192, 1152, 4608);
}